// Round 1
// baseline (895.426 us; speedup 1.0000x reference)
//
#include <hip/hip_runtime.h>

#define T_LEN 1024
#define HID   32
#define G4    128   // 4*HID gate rows
#define LDIM  16
#define BATCH 512
#define NTHREADS 384  // 3 layer groups x 128 gate rows

__device__ __forceinline__ float sigmoidf_fast(float x) {
    // exp(-x)=inf for very negative x -> 1/(1+inf)=0, safe.
    return 1.0f / (1.0f + __expf(-x));
}

__device__ __forceinline__ float tanhf_fast(float x) {
    // overflow-safe: exp arg always <= 0
    float s = fabsf(x);
    float t = __expf(-2.0f * s);
    float r = (1.0f - t) / (1.0f + t);
    return copysignf(r, x);
}

__global__ __launch_bounds__(NTHREADS, 3)
void lstm_encoder_kernel(const float* __restrict__ x,
                         const float* __restrict__ Wih0, const float* __restrict__ Whh0,
                         const float* __restrict__ bih0, const float* __restrict__ bhh0,
                         const float* __restrict__ Wih1, const float* __restrict__ Whh1,
                         const float* __restrict__ bih1, const float* __restrict__ bhh1,
                         const float* __restrict__ Wih2, const float* __restrict__ Whh2,
                         const float* __restrict__ bih2, const float* __restrict__ bhh2,
                         const float* __restrict__ Wm,  const float* __restrict__ bm,
                         const float* __restrict__ Wlv, const float* __restrict__ blv,
                         float* __restrict__ out)
{
    const int b   = blockIdx.x;   // one batch element per block
    const int tid = threadIdx.x;
    const int l   = tid >> 7;     // layer group 0..2 (wave-uniform: 128 = 2 waves)
    const int g   = tid & 127;    // gate row within layer

    __shared__ float  xs[T_LEN * 2];      // staged input sequence (8 KB)
    __shared__ float4 hbuf4[3][HID / 4];  // h state per layer (single-buffered)
    __shared__ float  gates[3][G4];       // activated gate scratch
    __shared__ float  cbuf[HID];          // final c of layer 2

    // ---- stage x (coalesced) ----
    const float* xb = x + (size_t)b * (T_LEN * 2);
    for (int i = tid; i < T_LEN * 2; i += NTHREADS) xs[i] = xb[i];

    // ---- zero h state ----
    if (tid < 3 * (HID / 4)) ((float4*)hbuf4)[tid] = make_float4(0.f, 0.f, 0.f, 0.f);

    // ---- per-thread weights into registers ----
    const float* Wih = (l == 0) ? Wih0 : (l == 1) ? Wih1 : Wih2;
    const float* Whh = (l == 0) ? Whh0 : (l == 1) ? Whh1 : Whh2;
    const float* bih = (l == 0) ? bih0 : (l == 1) ? bih1 : bih2;
    const float* bhh = (l == 0) ? bhh0 : (l == 1) ? bhh1 : bhh2;

    float wih[HID], whh[HID];
    if (l == 0) {
        wih[0] = Wih[g * 2 + 0];
        wih[1] = Wih[g * 2 + 1];
    } else {
#pragma unroll
        for (int k = 0; k < HID; ++k) wih[k] = Wih[g * HID + k];
    }
#pragma unroll
    for (int k = 0; k < HID; ++k) whh[k] = Whh[g * HID + k];
    const float bias = bih[g] + bhh[g];

    float c = 0.0f;  // cell state: only meaningful on update threads (g < HID)

    const float4* hself4 = hbuf4[l];
    const float4* hprev4 = (l > 0) ? hbuf4[l - 1] : hbuf4[0];

    __syncthreads();

    // ---- pipelined time loop: layer l processes t = s - l ----
    for (int s = 0; s < T_LEN + 2; ++s) {
        const int  t      = s - l;
        const bool active = (t >= 0) && (t < T_LEN);

        float act = 0.0f;
        if (active) {
            float acc = bias;
            if (l == 0) {
                acc += wih[0] * xs[t * 2 + 0] + wih[1] * xs[t * 2 + 1];
            } else {
#pragma unroll
                for (int q = 0; q < HID / 4; ++q) {
                    float4 a = hprev4[q];  // LDS broadcast read
                    acc += wih[4*q+0] * a.x + wih[4*q+1] * a.y
                         + wih[4*q+2] * a.z + wih[4*q+3] * a.w;
                }
            }
#pragma unroll
            for (int q = 0; q < HID / 4; ++q) {
                float4 hv = hself4[q];     // LDS broadcast read
                acc += whh[4*q+0] * hv.x + whh[4*q+1] * hv.y
                     + whh[4*q+2] * hv.z + whh[4*q+3] * hv.w;
            }
            // gate order i,f,g,o: rows [0,32) i / [32,64) f / [64,96) g(tanh) / [96,128) o
            act = (g >= 2 * HID && g < 3 * HID) ? tanhf_fast(acc) : sigmoidf_fast(acc);
            gates[l][g] = act;
        }
        __syncthreads();  // gates visible; separates h reads (above) from h writes (below)

        if (active && g < HID) {
            float iv = gates[l][g];
            float fv = gates[l][g + HID];
            float gv = gates[l][g + 2 * HID];
            float ov = gates[l][g + 3 * HID];
            c = fv * c + iv * gv;
            ((float*)hbuf4[l])[g] = ov * tanhf_fast(c);
        }
        __syncthreads();  // h writes visible for next step
    }

    // ---- final projection: mean / log_var from c3 ----
    if (l == 2 && g < HID) cbuf[g] = c;
    __syncthreads();

    if (tid < 2 * LDIM) {
        const bool  is_mean = (tid < LDIM);
        const int   j  = is_mean ? tid : tid - LDIM;
        const float* W = is_mean ? Wm  : Wlv;
        const float* B = is_mean ? bm  : blv;
        float acc = B[j];
#pragma unroll
        for (int k = 0; k < HID; ++k) acc += W[j * HID + k] * cbuf[k];
        const size_t off = (is_mean ? 0 : (size_t)BATCH * LDIM) + (size_t)b * LDIM + j;
        out[off] = acc;
    }
}

extern "C" void kernel_launch(void* const* d_in, const int* in_sizes, int n_in,
                              void* d_out, int out_size, void* d_ws, size_t ws_size,
                              hipStream_t stream) {
    const float* x    = (const float*)d_in[0];
    const float* Wih0 = (const float*)d_in[1];
    const float* Whh0 = (const float*)d_in[2];
    const float* bih0 = (const float*)d_in[3];
    const float* bhh0 = (const float*)d_in[4];
    const float* Wih1 = (const float*)d_in[5];
    const float* Whh1 = (const float*)d_in[6];
    const float* bih1 = (const float*)d_in[7];
    const float* bhh1 = (const float*)d_in[8];
    const float* Wih2 = (const float*)d_in[9];
    const float* Whh2 = (const float*)d_in[10];
    const float* bih2 = (const float*)d_in[11];
    const float* bhh2 = (const float*)d_in[12];
    const float* Wm   = (const float*)d_in[13];
    const float* bm   = (const float*)d_in[14];
    const float* Wlv  = (const float*)d_in[15];
    const float* blv  = (const float*)d_in[16];
    float* out = (float*)d_out;

    lstm_encoder_kernel<<<dim3(BATCH), dim3(NTHREADS), 0, stream>>>(
        x, Wih0, Whh0, bih0, bhh0, Wih1, Whh1, bih1, bhh1,
        Wih2, Whh2, bih2, bhh2, Wm, bm, Wlv, blv, out);
}

// Round 2
// 565.301 us; speedup vs baseline: 1.5840x; 1.5840x over previous
//
#include <hip/hip_runtime.h>

#define T_LEN 1024
#define HID   32
#define LDIM  16
#define BATCH 512
#define NT    384   // 3 layers x 2 waves x 64 lanes

typedef _Float16 h2 __attribute__((ext_vector_type(2)));

#if defined(__has_builtin)
#if __has_builtin(__builtin_amdgcn_fdot2)
#define HAVE_FDOT2 1
#endif
#if __has_builtin(__builtin_amdgcn_rcpf)
#define FAST_RCP(x) __builtin_amdgcn_rcpf(x)
#endif
#endif
#ifndef FAST_RCP
#define FAST_RCP(x) (1.0f / (x))
#endif

__device__ __forceinline__ float dot2acc(unsigned w, unsigned h, float acc) {
#ifdef HAVE_FDOT2
    return __builtin_amdgcn_fdot2(__builtin_bit_cast(h2, w),
                                  __builtin_bit_cast(h2, h), acc, false);
#else
    h2 a = __builtin_bit_cast(h2, w);
    h2 b = __builtin_bit_cast(h2, h);
    return acc + (float)a[0] * (float)b[0] + (float)a[1] * (float)b[1];
#endif
}

__device__ __forceinline__ unsigned packh2(float a, float b) {
    h2 v;
    v[0] = (_Float16)a;
    v[1] = (_Float16)b;
    return __builtin_bit_cast(unsigned, v);
}

__global__ __launch_bounds__(NT, 3)
void lstm_encoder_kernel(const float* __restrict__ x,
                         const float* __restrict__ Wih0, const float* __restrict__ Whh0,
                         const float* __restrict__ bih0, const float* __restrict__ bhh0,
                         const float* __restrict__ Wih1, const float* __restrict__ Whh1,
                         const float* __restrict__ bih1, const float* __restrict__ bhh1,
                         const float* __restrict__ Wih2, const float* __restrict__ Whh2,
                         const float* __restrict__ bih2, const float* __restrict__ bhh2,
                         const float* __restrict__ Wm,  const float* __restrict__ bm,
                         const float* __restrict__ Wlv, const float* __restrict__ blv,
                         float* __restrict__ out)
{
    const int b    = blockIdx.x;
    const int tid  = threadIdx.x;
    const int lane = tid & 63;
    const int wave = tid >> 6;      // 0..5
    const int l    = wave >> 1;     // layer 0..2 (wave-uniform)
    const int wv   = wave & 1;      // which 16-element group
    const int q    = lane >> 4;     // gate index 0..3 (i,f,g,o)
    const int jj   = lane & 15;
    const int j    = wv * 16 + jj;  // h-element 0..31
    const int r    = q * 32 + j;    // gate row 0..127 (torch order)

    __shared__ float xs[T_LEN * 2];                      // 8 KB input stage
    __shared__ __align__(16) _Float16 hbuf[2][3][HID];   // double-buffered h (f16)
    __shared__ float cbuf[HID];

    // ---- stage x (coalesced) ----
    const float* xb = x + (size_t)b * (T_LEN * 2);
    for (int i = tid; i < T_LEN * 2; i += NT) xs[i] = xb[i];
    // ---- zero h buffers (2*3*32 halfs = 96 dwords) ----
    if (tid < 96) ((unsigned*)hbuf)[tid] = 0u;

    // ---- per-thread weights -> packed f16 register pairs ----
    const float* Wih = (l == 0) ? Wih0 : (l == 1) ? Wih1 : Wih2;
    const float* Whh = (l == 0) ? Whh0 : (l == 1) ? Whh1 : Whh2;
    const float* bih = (l == 0) ? bih0 : (l == 1) ? bih1 : bih2;
    const float* bhh = (l == 0) ? bhh0 : (l == 1) ? bhh1 : bhh2;

    unsigned whhp[16], wihp[16];
    float wx0 = 0.f, wx1 = 0.f;
#pragma unroll
    for (int k = 0; k < 16; ++k)
        whhp[k] = packh2(Whh[r * HID + 2 * k], Whh[r * HID + 2 * k + 1]);
    if (l == 0) {
        wx0 = Wih[r * 2 + 0];
        wx1 = Wih[r * 2 + 1];
#pragma unroll
        for (int k = 0; k < 16; ++k) wihp[k] = 0u;
    } else {
#pragma unroll
        for (int k = 0; k < 16; ++k)
            wihp[k] = packh2(Wih[r * HID + 2 * k], Wih[r * HID + 2 * k + 1]);
    }
    const float bias = bih[r] + bhh[r];

    // pin weights in VGPRs (prevent rematerialized loads inside the loop)
#pragma unroll
    for (int k = 0; k < 16; ++k) asm volatile("" : "+v"(whhp[k]));
#pragma unroll
    for (int k = 0; k < 16; ++k) asm volatile("" : "+v"(wihp[k]));

    // unified activation: y = m * sigmoid(k*x) + a   (tanh(x) = 2*sigmoid(2x)-1)
    const float kneg = (q == 2) ? -2.0f : -1.0f;
    const float mm   = (q == 2) ?  2.0f :  1.0f;
    const float aa   = (q == 2) ? -1.0f :  0.0f;

    float c = 0.0f;  // cell state for element j (replicated across the 4 q-lanes)

    __syncthreads();

    for (int s = 0; s < T_LEN + 2; ++s) {
        const int t = s - l;
        const bool active = ((unsigned)t < (unsigned)T_LEN);  // wave-uniform

        if (active) {
            const unsigned* hs = (const unsigned*)hbuf[s & 1][l];
            const unsigned* hp = (const unsigned*)hbuf[s & 1][(l > 0) ? (l - 1) : 0];

            float a0 = bias, a1 = 0.f, a2 = 0.f, a3 = 0.f;
            if (l == 0) {
                a0 = fmaf(wx0, xs[2 * t], a0);
                a0 = fmaf(wx1, xs[2 * t + 1], a0);
            } else {
#pragma unroll
                for (int k = 0; k < 16; k += 4) {
                    a0 = dot2acc(wihp[k + 0], hp[k + 0], a0);
                    a1 = dot2acc(wihp[k + 1], hp[k + 1], a1);
                    a2 = dot2acc(wihp[k + 2], hp[k + 2], a2);
                    a3 = dot2acc(wihp[k + 3], hp[k + 3], a3);
                }
            }
#pragma unroll
            for (int k = 0; k < 16; k += 4) {
                a0 = dot2acc(whhp[k + 0], hs[k + 0], a0);
                a1 = dot2acc(whhp[k + 1], hs[k + 1], a1);
                a2 = dot2acc(whhp[k + 2], hs[k + 2], a2);
                a3 = dot2acc(whhp[k + 3], hs[k + 3], a3);
            }
            const float pre = (a0 + a1) + (a2 + a3);

            // activated gate for row r
            const float e = __expf(kneg * pre);
            const float y = fmaf(mm, FAST_RCP(1.0f + e), aa);

            // gather the 4 gates of element j (in-wave; rows live at lanes q'*16+jj)
            const float iv = __shfl(y, jj +  0, 64);
            const float fv = __shfl(y, jj + 16, 64);
            const float gv = __shfl(y, jj + 32, 64);
            const float ov = __shfl(y, jj + 48, 64);

            c = fmaf(fv, c, iv * gv);
            const float e2 = __expf(-2.0f * c);
            const float th = fmaf(2.0f, FAST_RCP(1.0f + e2), -1.0f);
            const float h  = ov * th;
            if (q == 0) hbuf[(s + 1) & 1][l][j] = (_Float16)h;
        }
        __syncthreads();  // single barrier: h double-buffered, gates in-wave
    }

    if (l == 2 && q == 0) cbuf[j] = c;
    __syncthreads();

    // ---- final projection: mean / log_var from c3 ----
    if (tid < 2 * LDIM) {
        const bool   is_mean = (tid < LDIM);
        const int    jo = is_mean ? tid : tid - LDIM;
        const float* W  = is_mean ? Wm  : Wlv;
        const float* Bb = is_mean ? bm  : blv;
        float acc = Bb[jo];
#pragma unroll
        for (int k = 0; k < HID; ++k) acc = fmaf(W[jo * HID + k], cbuf[k], acc);
        const size_t off = (is_mean ? 0 : (size_t)BATCH * LDIM) + (size_t)b * LDIM + jo;
        out[off] = acc;
    }
}

extern "C" void kernel_launch(void* const* d_in, const int* in_sizes, int n_in,
                              void* d_out, int out_size, void* d_ws, size_t ws_size,
                              hipStream_t stream) {
    const float* x    = (const float*)d_in[0];
    const float* Wih0 = (const float*)d_in[1];
    const float* Whh0 = (const float*)d_in[2];
    const float* bih0 = (const float*)d_in[3];
    const float* bhh0 = (const float*)d_in[4];
    const float* Wih1 = (const float*)d_in[5];
    const float* Whh1 = (const float*)d_in[6];
    const float* bih1 = (const float*)d_in[7];
    const float* bhh1 = (const float*)d_in[8];
    const float* Wih2 = (const float*)d_in[9];
    const float* Whh2 = (const float*)d_in[10];
    const float* bih2 = (const float*)d_in[11];
    const float* bhh2 = (const float*)d_in[12];
    const float* Wm   = (const float*)d_in[13];
    const float* bm   = (const float*)d_in[14];
    const float* Wlv  = (const float*)d_in[15];
    const float* blv  = (const float*)d_in[16];
    float* out = (float*)d_out;

    lstm_encoder_kernel<<<dim3(BATCH), dim3(NT), 0, stream>>>(
        x, Wih0, Whh0, bih0, bhh0, Wih1, Whh1, bih1, bhh1,
        Wih2, Whh2, bih2, bhh2, Wm, bm, Wlv, blv, out);
}

// Round 4
// 530.232 us; speedup vs baseline: 1.6887x; 1.0661x over previous
//
#include <hip/hip_runtime.h>

#define T_LEN 1024
#define HID   32
#define LDIM  16
#define BATCH 512
#define NT    384   // 3 layers x 2 waves x 64 lanes

typedef _Float16 h2 __attribute__((ext_vector_type(2)));
typedef unsigned int u32;

#if defined(__has_builtin)
#if __has_builtin(__builtin_amdgcn_fdot2)
#define HAVE_FDOT2 1
#endif
#if __has_builtin(__builtin_amdgcn_rcpf)
#define FAST_RCP(x) __builtin_amdgcn_rcpf(x)
#endif
#endif
#ifndef FAST_RCP
#define FAST_RCP(x) (1.0f / (x))
#endif

__device__ __forceinline__ float dot2acc(u32 w, u32 h, float acc) {
#ifdef HAVE_FDOT2
    return __builtin_amdgcn_fdot2(__builtin_bit_cast(h2, w),
                                  __builtin_bit_cast(h2, h), acc, false);
#else
    h2 a = __builtin_bit_cast(h2, w);
    h2 b = __builtin_bit_cast(h2, h);
    return acc + (float)a[0] * (float)b[0] + (float)a[1] * (float)b[1];
#endif
}

__device__ __forceinline__ u32 packh2(float a, float b) {
    h2 v;
    v[0] = (_Float16)a;
    v[1] = (_Float16)b;
    return __builtin_bit_cast(u32, v);
}

// BitMode ds_swizzle: dst lane reads src lane ((lane&and)|or)^xor within 32-lane groups
template <int OFF>
__device__ __forceinline__ float swz(float v) {
    return __builtin_bit_cast(float,
        __builtin_amdgcn_ds_swizzle(__builtin_bit_cast(int, v), OFF));
}

__global__ __launch_bounds__(NT, 3)
void lstm_encoder_kernel(const float* __restrict__ x,
                         const float* __restrict__ Wih0, const float* __restrict__ Whh0,
                         const float* __restrict__ bih0, const float* __restrict__ bhh0,
                         const float* __restrict__ Wih1, const float* __restrict__ Whh1,
                         const float* __restrict__ bih1, const float* __restrict__ bhh1,
                         const float* __restrict__ Wih2, const float* __restrict__ Whh2,
                         const float* __restrict__ bih2, const float* __restrict__ bhh2,
                         const float* __restrict__ Wm,  const float* __restrict__ bm,
                         const float* __restrict__ Wlv, const float* __restrict__ blv,
                         float* __restrict__ out)
{
    const int b    = blockIdx.x;
    const int tid  = threadIdx.x;
    const int lane = tid & 63;
    const int wave = tid >> 6;            // 0..5
    const int l    = wave >> 1;           // layer 0..2 (wave-uniform)
    const int wv   = wave & 1;            // which 16-element group
    const int q    = (lane >> 3) & 3;     // role: 0=i 1=g 2=f 3=o (bits 3,4)
    const int e    = (lane & 7) | ((lane >> 2) & 8);  // element 0..15 (bits 0-2, 5)
    const int j    = wv * 16 + e;         // h element 0..31
    // torch gate-row: i rows 0-31, f 32-63, g 64-95, o 96-127
    const int r = ((q & 1) ? 64 : 0) + ((q & 2) ? 32 : 0) + j;

    __shared__ float xs[T_LEN * 2];                     // 8 KB input stage
    __shared__ __align__(16) _Float16 hb0[3][HID];      // h, buffer parity 0
    __shared__ __align__(16) _Float16 hb1[3][HID];      // h, buffer parity 1
    __shared__ float cbuf[HID];

    // ---- stage x (coalesced, vectorized) ----
    const float4* xb4 = (const float4*)(x + (size_t)b * (T_LEN * 2));
    for (int i = tid; i < (T_LEN * 2) / 4; i += NT) ((float4*)xs)[i] = xb4[i];

    // ---- zero h buffers (48 dwords each) ----
    if (tid < 48)       ((u32*)hb0)[tid]      = 0u;
    else if (tid < 96)  ((u32*)hb1)[tid - 48] = 0u;

    // ---- per-thread weights -> packed f16, order [wih(16) | whh(16)] ----
    const float* Wih = (l == 0) ? Wih0 : (l == 1) ? Wih1 : Wih2;
    const float* Whh = (l == 0) ? Whh0 : (l == 1) ? Whh1 : Whh2;
    const float* bih = (l == 0) ? bih0 : (l == 1) ? bih1 : bih2;
    const float* bhh = (l == 0) ? bhh0 : (l == 1) ? bhh1 : bhh2;

    u32 wpack[32];
    float wx0 = 0.f, wx1 = 0.f;
#pragma unroll
    for (int k = 0; k < 16; ++k)
        wpack[16 + k] = packh2(Whh[r * HID + 2 * k], Whh[r * HID + 2 * k + 1]);
    if (l == 0) {
        wx0 = Wih[r * 2 + 0];
        wx1 = Wih[r * 2 + 1];
#pragma unroll
        for (int k = 0; k < 16; ++k) wpack[k] = 0u;
    } else {
#pragma unroll
        for (int k = 0; k < 16; ++k)
            wpack[k] = packh2(Wih[r * HID + 2 * k], Wih[r * HID + 2 * k + 1]);
    }
    const float bias = bih[r] + bhh[r];
#pragma unroll
    for (int k = 0; k < 32; ++k) asm volatile("" : "+v"(wpack[k]));

    // unified activation: y = mm * sigmoid(kk*x) + aa  (tanh(x) = 2*sigmoid(2x)-1)
    const bool  is_g = (q == 1);
    const float kneg = is_g ? -2.0f : -1.0f;
    const float mm   = is_g ?  2.0f :  1.0f;
    const float aa   = is_g ? -1.0f :  0.0f;

    float c = 0.0f;  // cell value: exact on q2 lanes; bounded garbage elsewhere

    __syncthreads();

#define STEP(RD, WR, S)                                                          \
    do {                                                                         \
        const int t_ = (S) - l;                                                  \
        if ((unsigned)t_ < (unsigned)T_LEN) {                                    \
            float a0 = bias, a1 = 0.f, a2 = 0.f, a3 = 0.f;                       \
            if (l == 0) {                                                        \
                const float2 xv = *(const float2*)&xs[2 * t_];                   \
                a0 = fmaf(wx0, xv.x, a0);                                        \
                a1 = fmaf(wx1, xv.y, a1);                                        \
                const uint4* hv = (const uint4*)&RD[0][0];                       \
                _Pragma("unroll")                                                \
                for (int k = 0; k < 4; ++k) {                                    \
                    const uint4 h = hv[k];                                       \
                    a0 = dot2acc(wpack[16 + 4 * k + 0], h.x, a0);                \
                    a1 = dot2acc(wpack[16 + 4 * k + 1], h.y, a1);                \
                    a2 = dot2acc(wpack[16 + 4 * k + 2], h.z, a2);                \
                    a3 = dot2acc(wpack[16 + 4 * k + 3], h.w, a3);                \
                }                                                                \
            } else {                                                             \
                const uint4* hv = (const uint4*)&RD[l - 1][0];                   \
                _Pragma("unroll")                                                \
                for (int k = 0; k < 8; ++k) {                                    \
                    const uint4 h = hv[k];                                       \
                    a0 = dot2acc(wpack[4 * k + 0], h.x, a0);                     \
                    a1 = dot2acc(wpack[4 * k + 1], h.y, a1);                     \
                    a2 = dot2acc(wpack[4 * k + 2], h.z, a2);                     \
                    a3 = dot2acc(wpack[4 * k + 3], h.w, a3);                     \
                }                                                                \
            }                                                                    \
            const float pre = (a0 + a1) + (a2 + a3);                             \
            const float ex  = __expf(kneg * pre);                                \
            const float y   = fmaf(mm, FAST_RCP(1.0f + ex), aa);                 \
            const float y1  = swz<0x201F>(y);        /* xor-8: i<->g, f<->o */   \
            const float P   = y * y1;                /* i*g on q0/q1 lanes  */   \
            const float v   = (q < 2) ? P : y;                                   \
            const float z   = swz<0x401F>(v);        /* xor-16: q0<->q2, q1<->q3 */ \
            c = fmaf(y, c, z);                       /* on q2: f*c + i*g */      \
            const float e2 = __expf(-2.0f * c);                                  \
            const float th = fmaf(2.0f, FAST_RCP(1.0f + e2), -1.0f);             \
            if (q == 2) WR[l][j] = (_Float16)(y1 * th); /* y1 = o on q2 */       \
        }                                                                        \
        __syncthreads();                                                         \
    } while (0)

    for (int s = 0; s < T_LEN + 2; s += 2) {
        STEP(hb0, hb1, s);
        STEP(hb1, hb0, s + 1);
    }
#undef STEP

    if (l == 2 && q == 2) cbuf[j] = c;
    __syncthreads();

    // ---- final projection: mean / log_var from c3 ----
    if (tid < 2 * LDIM) {
        const bool   is_mean = (tid < LDIM);
        const int    jo = is_mean ? tid : tid - LDIM;
        const float* W  = is_mean ? Wm  : Wlv;
        const float* Bb = is_mean ? bm  : blv;
        float acc = Bb[jo];
#pragma unroll
        for (int k = 0; k < HID; ++k) acc = fmaf(W[jo * HID + k], cbuf[k], acc);
        const size_t off = (is_mean ? 0 : (size_t)BATCH * LDIM) + (size_t)b * LDIM + jo;
        out[off] = acc;
    }
}

extern "C" void kernel_launch(void* const* d_in, const int* in_sizes, int n_in,
                              void* d_out, int out_size, void* d_ws, size_t ws_size,
                              hipStream_t stream) {
    const float* x    = (const float*)d_in[0];
    const float* Wih0 = (const float*)d_in[1];
    const float* Whh0 = (const float*)d_in[2];
    const float* bih0 = (const float*)d_in[3];
    const float* bhh0 = (const float*)d_in[4];
    const float* Wih1 = (const float*)d_in[5];
    const float* Whh1 = (const float*)d_in[6];
    const float* bih1 = (const float*)d_in[7];
    const float* bhh1 = (const float*)d_in[8];
    const float* Wih2 = (const float*)d_in[9];
    const float* Whh2 = (const float*)d_in[10];
    const float* bih2 = (const float*)d_in[11];
    const float* bhh2 = (const float*)d_in[12];
    const float* Wm   = (const float*)d_in[13];
    const float* bm   = (const float*)d_in[14];
    const float* Wlv  = (const float*)d_in[15];
    const float* blv  = (const float*)d_in[16];
    float* out = (float*)d_out;

    lstm_encoder_kernel<<<dim3(BATCH), dim3(NT), 0, stream>>>(
        x, Wih0, Whh0, bih0, bhh0, Wih1, Whh1, bih1, bhh1,
        Wih2, Whh2, bih2, bhh2, Wm, bm, Wlv, blv, out);
}